// Round 13
// baseline (2252.187 us; speedup 1.0000x reference)
//
#include <hip/hip_runtime.h>

#define H 64
#define FN 5
#define EPB 4096        // edges per scatter block
#define BSHIFT 7        // bucket = dst >> 7 (128 nodes per bucket)
#define CAPB 2600       // per-bucket edge staging (mean 2048, +12 sigma)

typedef _Float16 half4 __attribute__((ext_vector_type(4)));
typedef _Float16 half8 __attribute__((ext_vector_type(8)));

// ================= scatter: slab-local bucket-sorted packed edges =================
// packed entry: src (17b) | dst_local (7b) << 17
__global__ void k_bscatter2(const int* __restrict__ src, const int* __restrict__ dst,
                            int* __restrict__ lofs_g, int* __restrict__ bcounts,
                            int* __restrict__ binned, int nE, int nbB) {
    __shared__ int lh[1024], lpos[1024], lcur[1024], tmp[256];
    __shared__ int stage[EPB];             // 16 KB
    int t = threadIdx.x;
    int e0 = blockIdx.x * EPB;
    int es[16], ed[16];
    for (int i = t; i < 1024; i += 256) lh[i] = 0;
    __syncthreads();
#pragma unroll
    for (int i = 0; i < 16; ++i) {
        int e = e0 + i * 256 + t;
        bool v = e < nE;
        es[i] = v ? src[e] : 0;
        ed[i] = v ? dst[e] : -1;
        if (v) atomicAdd(&lh[ed[i] >> BSHIFT], 1);
    }
    __syncthreads();
    // quad-sum exclusive scan of lh[0..1023] -> lpos
    int b0 = lh[4 * t], b1 = lh[4 * t + 1], b2 = lh[4 * t + 2], b3 = lh[4 * t + 3];
    int s4 = b0 + b1 + b2 + b3;
    tmp[t] = s4;
    __syncthreads();
    for (int s = 1; s < 256; s <<= 1) {
        int a = (t >= s) ? tmp[t - s] : 0;
        __syncthreads();
        tmp[t] += a;
        __syncthreads();
    }
    int ex = tmp[t] - s4;
    lpos[4 * t] = ex;
    lpos[4 * t + 1] = ex + b0;
    lpos[4 * t + 2] = ex + b0 + b1;
    lpos[4 * t + 3] = ex + b0 + b1 + b2;
    __syncthreads();
    for (int i = t; i < 1024; i += 256) lcur[i] = lpos[i];
    size_t row = (size_t)blockIdx.x * (nbB + 1);
    for (int b = t; b <= nbB; b += 256) lofs_g[row + b] = lpos[b];
    for (int b = t; b < nbB; b += 256) if (lh[b]) atomicAdd(&bcounts[b], lh[b]);
    __syncthreads();
#pragma unroll
    for (int i = 0; i < 16; ++i) {
        if (ed[i] >= 0) {
            int b = ed[i] >> BSHIFT;
            int p = atomicAdd(&lcur[b], 1);
            stage[p] = es[i] | ((ed[i] & 127) << 17);
        }
    }
    __syncthreads();
    int total = lpos[nbB];
    for (int j = t; j < total; j += 256) binned[e0 + j] = stage[j];   // coalesced
}

// ================= bprep: bucket-grouped edges + dinv + fused encoder =================
// block B = bucket B (128 nodes). Gathers its runs via binary-search coalesced
// copy straight to gedges[ebase..], histograms degrees -> dinv, then computes
// g0 = fp16(dinv * relu(x@Wn+bn)) for its nodes (encoder fused; k_enc deleted).
__global__ void k_bprep(const int* __restrict__ binned, const int* __restrict__ lofs_g,
                        const int* __restrict__ bcounts,
                        const float* __restrict__ x, const float* __restrict__ Wn,
                        const float* __restrict__ bn,
                        int* __restrict__ gedges, int* __restrict__ ebase_g,
                        float* __restrict__ dinv, _Float16* __restrict__ g0,
                        int n, int nE, int nbE, int nbB) {
    __shared__ int runlen[512], runstart[512], roff[512], tmp[256];
    __shared__ int deg[128];
    __shared__ int sh_base, sh_total;
    __shared__ float xs[128 * FN], WnS[FN * H], bnS[H], dv_s[128];
    int t = threadIdx.x;
    int B = blockIdx.x;
    int node0 = B << BSHIFT;
    int nn = min(128, n - node0);

    // base = sum(bcounts[0..B)); zero deg/runlen in same phase
    int myb = 0;
    for (int b = t; b < B; b += 256) myb += bcounts[b];
    tmp[t] = myb;
    if (t < 128) deg[t] = 0;
    runlen[t] = 0; runlen[t + 256] = 0;
    __syncthreads();
    for (int s = 128; s > 0; s >>= 1) {
        if (t < s) tmp[t] += tmp[t + s];
        __syncthreads();
    }
    if (t == 0) sh_base = tmp[0];
    __syncthreads();                       // tmp free, sh_base visible

    for (int sb = t; sb < nbE; sb += 256) {
        size_t row = (size_t)sb * (nbB + 1);
        int o0 = lofs_g[row + B], o1 = lofs_g[row + B + 1];
        runlen[sb] = o1 - o0;
        runstart[sb] = sb * EPB + o0;
    }
    __syncthreads();
    int a0 = runlen[2 * t], a1 = runlen[2 * t + 1];
    tmp[t] = a0 + a1;
    __syncthreads();
    for (int s = 1; s < 256; s <<= 1) {
        int a = (t >= s) ? tmp[t - s] : 0;
        __syncthreads();
        tmp[t] += a;
        __syncthreads();
    }
    int ex = tmp[t] - (a0 + a1);
    roff[2 * t] = ex;
    roff[2 * t + 1] = ex + a0;
    if (t == 255) sh_total = tmp[255];
    __syncthreads();
    int total = sh_total;
    int base = sh_base;

    // coalesced run copy straight to gedges + degree histogram
    for (int j = t; j < total; j += 256) {
        int lo = 0, hi = nbE - 1;
        while (lo < hi) {
            int mid = (lo + hi + 1) >> 1;
            if (roff[mid] <= j) lo = mid; else hi = mid - 1;
        }
        int v = binned[runstart[lo] + (j - roff[lo])];
        gedges[base + j] = v;
        atomicAdd(&deg[(v >> 17) & 127], 1);
    }
    if (t == 0) {
        ebase_g[B] = base;
        if (B == nbB - 1) ebase_g[nbB] = base + total;
    }
    // encoder staging
    for (int idx = t; idx < nn * FN; idx += 256) xs[idx] = x[(size_t)node0 * FN + idx];
    for (int idx = t; idx < FN * H; idx += 256) WnS[idx] = Wn[idx];
    if (t < H) bnS[t] = bn[t];
    __syncthreads();
    if (t < 128) {
        float dv = 1.0f / sqrtf((float)deg[t] + 1.0f);
        dv_s[t] = dv;
        if (t < nn) dinv[node0 + t] = dv;
    }
    __syncthreads();
    for (int idx = t; idx < nn * H; idx += 256) {
        int r = idx >> 6, ch = idx & 63;
        float a = bnS[ch];
#pragma unroll
        for (int f = 0; f < FN; ++f) a += xs[r * FN + f] * WnS[f * H + ch];
        g0[(size_t)(node0 + r) * H + ch] = (_Float16)(fmaxf(a, 0.f) * dv_s[r]);
    }
}

// ================= layer: edge-parallel bucket aggregation + GEMM =================
// block = bucket (128 nodes), 256 threads. Edges staged to LDS, then waves
// stream them 8-at-a-time (slot = lane&7, ch-group = lane>>3), dual-stream,
// ds_add_f32 into acc[dst_local] (stride 65: GEMM A-reads conflict-free,
// atomic banks ~2-way). NO per-node loops -> degree skew irrelevant; one
// drain point per bucket. Then self+dinv scale, 8x4 register-tile GEMM
// (W global, L1-hot), fused relu/bias/dinv epilogue.
__global__ void k_layerB(const _Float16* __restrict__ gin, const int* __restrict__ gedges,
                         const int* __restrict__ ebase_g, const float* __restrict__ dinv,
                         const float* __restrict__ W, const float* __restrict__ bias,
                         _Float16* __restrict__ gout, float* __restrict__ hout,
                         int n, int last) {
    __shared__ float acc[128 * 65];        // 33.3 KB
    __shared__ int lbuf[CAPB];             // 10.4 KB
    __shared__ float dv_s[128];
    int t = threadIdx.x;
    int B = blockIdx.x;
    int node0 = B << BSHIFT;
    int nn = min(128, n - node0);
    int e0 = ebase_g[B], e1 = ebase_g[B + 1];
    int total = e1 - e0;
    int lim = min(total, CAPB);
    for (int i = t; i < 128 * 65; i += 256) acc[i] = 0.f;
    for (int i = t; i < lim; i += 256) lbuf[i] = gedges[e0 + i];
    if (t < 128) dv_s[t] = (t < nn) ? dinv[node0 + t] : 0.f;
    __syncthreads();

    int wave = t >> 6, lane = t & 63;
    int c8 = (lane >> 3) * 8;
    int slot = lane & 7;
    // wave w owns 8-edge chunks c == w (mod 4); dual-stream pairs (c, c+4)
    int i = wave * 8;
    while (i + 40 <= lim) {
        int pA = lbuf[i + slot];
        int pB = lbuf[i + 32 + slot];
        int xA = pA & 0x1FFFF, dA = (pA >> 17) & 127;
        int xB = pB & 0x1FFFF, dB = (pB >> 17) & 127;
        half8 vA = *(const half8*)(gin + (size_t)xA * H + c8);
        half8 vB = *(const half8*)(gin + (size_t)xB * H + c8);
        int aA = dA * 65 + c8, aB = dB * 65 + c8;
#pragma unroll
        for (int k = 0; k < 8; ++k) {
            atomicAdd(&acc[aA + k], (float)vA[k]);
            atomicAdd(&acc[aB + k], (float)vB[k]);
        }
        i += 64;
    }
    while (i + 8 <= lim) {
        int p = lbuf[i + slot];
        int x = p & 0x1FFFF, d = (p >> 17) & 127;
        half8 v = *(const half8*)(gin + (size_t)x * H + c8);
        int a = d * 65 + c8;
#pragma unroll
        for (int k = 0; k < 8; ++k) atomicAdd(&acc[a + k], (float)v[k]);
        i += 32;
    }
    if (i + slot < lim) {
        int p = lbuf[i + slot];
        int x = p & 0x1FFFF, d = (p >> 17) & 127;
        half8 v = *(const half8*)(gin + (size_t)x * H + c8);
        int a = d * 65 + c8;
#pragma unroll
        for (int k = 0; k < 8; ++k) atomicAdd(&acc[a + k], (float)v[k]);
    }
    // overflow (statistically never): straight from global
    for (int j = lim + wave * 8; j < total; j += 32) {
        if (j + slot < total) {
            int p = gedges[e0 + j + slot];
            int x = p & 0x1FFFF, d = (p >> 17) & 127;
            half8 v = *(const half8*)(gin + (size_t)x * H + c8);
            int a = d * 65 + c8;
#pragma unroll
            for (int k = 0; k < 8; ++k) atomicAdd(&acc[a + k], (float)v[k]);
        }
    }
    __syncthreads();

    // self term + dinv scale (in place)
    for (int idx = t; idx < nn * H; idx += 256) {
        int r = idx >> 6, ch = idx & 63;
        float s = (acc[r * 65 + ch] + (float)gin[(size_t)(node0 + r) * H + ch]) * dv_s[r];
        acc[r * 65 + ch] = s;
    }
    __syncthreads();

    // GEMM: thread (tx,ty) -> rows 8*ty+rr (rr=0..7), cols tx*4..+3
    int tx = t & 15, ty = t >> 4;
    int c0 = tx * 4;
    float4 av[8];
#pragma unroll
    for (int rr = 0; rr < 8; ++rr) av[rr] = make_float4(0.f, 0.f, 0.f, 0.f);
#pragma unroll 8
    for (int k = 0; k < H; ++k) {
        float4 w = *(const float4*)(W + k * H + c0);
#pragma unroll
        for (int rr = 0; rr < 8; ++rr) {
            float v = acc[(8 * ty + rr) * 65 + k];
            av[rr].x += v * w.x; av[rr].y += v * w.y;
            av[rr].z += v * w.z; av[rr].w += v * w.w;
        }
    }
    float4 b = *(const float4*)(bias + c0);
#pragma unroll
    for (int rr = 0; rr < 8; ++rr) {
        int r = 8 * ty + rr;
        int rowi = node0 + r;
        if (rowi < n) {
            float4 o;
            o.x = fmaxf(av[rr].x + b.x, 0.f);
            o.y = fmaxf(av[rr].y + b.y, 0.f);
            o.z = fmaxf(av[rr].z + b.z, 0.f);
            o.w = fmaxf(av[rr].w + b.w, 0.f);
            if (last) {
                *(float4*)(hout + (size_t)rowi * H + c0) = o;
            } else {
                float d = dv_s[r];
                half4 hh;
                hh.x = (_Float16)(o.x * d);
                hh.y = (_Float16)(o.y * d);
                hh.z = (_Float16)(o.z * d);
                hh.w = (_Float16)(o.w * d);
                *(half4*)(gout + (size_t)rowi * H + c0) = hh;
            }
        }
    }
}

// ================= heads (lane = node) =================
__global__ void k_heads(const float* __restrict__ h,
                        const float* __restrict__ Wd1, const float* __restrict__ bd1,
                        const float* __restrict__ Wd2, const float* __restrict__ bd2,
                        const float* __restrict__ Wi1, const float* __restrict__ bi1,
                        const float* __restrict__ Wi2, const float* __restrict__ bi2,
                        float* __restrict__ out, int n) {
    __shared__ float hs[64 * 65];
    int lane = threadIdx.x;          // blockDim = 64
    int base = blockIdx.x * 64;
    for (int r = 0; r < 64; ++r) {
        int row = base + r;
        hs[r * 65 + lane] = (row < n) ? h[(size_t)row * H + lane] : 0.f;
    }
    __syncthreads();

    float accd[32], acci[32];
#pragma unroll
    for (int j = 0; j < 32; ++j) { accd[j] = bd1[j]; acci[j] = bi1[j]; }
    for (int k = 0; k < H; ++k) {
        float hk = hs[lane * 65 + k];
#pragma unroll
        for (int j = 0; j < 32; ++j) {
            accd[j] += hk * Wd1[k * 32 + j];
            acci[j] += hk * Wi1[k * 32 + j];
        }
    }
    float demand = bd2[0], inventory = bi2[0];
#pragma unroll
    for (int j = 0; j < 32; ++j) {
        demand    += fmaxf(accd[j], 0.f) * Wd2[j];
        inventory += fmaxf(acci[j], 0.f) * Wi2[j];
    }
    int node = base + lane;
    if (node < n) {
        out[node] = demand;
        out[n + node] = inventory;
    }
}

extern "C" void kernel_launch(void* const* d_in, const int* in_sizes, int n_in,
                              void* d_out, int out_size, void* d_ws, size_t ws_size,
                              hipStream_t stream) {
    const float* x   = (const float*)d_in[0];
    const int*   ei  = (const int*)  d_in[1];
    // d_in[2] = edge_attr, d_in[5] = We, d_in[6] = be : dead code in reference.
    const float* Wn  = (const float*)d_in[3];
    const float* bn  = (const float*)d_in[4];
    const float* Wc  = (const float*)d_in[7];   // [3,64,64]
    const float* bc  = (const float*)d_in[8];   // [3,64]
    const float* Wd1 = (const float*)d_in[9];
    const float* bd1 = (const float*)d_in[10];
    const float* Wd2 = (const float*)d_in[11];
    const float* bd2 = (const float*)d_in[12];
    const float* Wi1 = (const float*)d_in[13];
    const float* bi1 = (const float*)d_in[14];
    const float* Wi2 = (const float*)d_in[15];
    const float* bi2 = (const float*)d_in[16];

    const int n  = in_sizes[0] / FN;   // 100000
    const int nE = in_sizes[1] / 2;    // 1600000
    const int* src = ei;
    const int* dst = ei + nE;

    const int nbE = (nE + EPB - 1) / EPB;       // 391 scatter blocks
    const int nbB = (n + 127) >> BSHIFT;        // 782 buckets

    char* w = (char*)d_ws;
    int* binned    = (int*)w;   w += (size_t)nbE * EPB * 4;
    int* gedges    = (int*)w;   w += (size_t)nE * 4;
    int* lofs      = (int*)w;   w += (size_t)nbE * (nbB + 1) * 4;
    int* bcounts   = (int*)w;   w += 1024 * 4;
    int* ebase     = (int*)w;   w += 1024 * 4;
    float* dinv    = (float*)w; w += (size_t)n * 4;
    float* hbuf    = (float*)w; w += (size_t)n * H * 4;
    _Float16* gA   = (_Float16*)w; w += (size_t)n * H * 2;
    _Float16* gB   = (_Float16*)w; w += (size_t)n * H * 2;

    hipMemsetAsync(bcounts, 0, 1024 * 4, stream);

    k_bscatter2<<<nbE, 256, 0, stream>>>(src, dst, lofs, bcounts, binned, nE, nbB);
    k_bprep    <<<nbB, 256, 0, stream>>>(binned, lofs, bcounts, x, Wn, bn,
                                         gedges, ebase, dinv, gA, n, nE, nbE, nbB);

    k_layerB<<<nbB, 256, 0, stream>>>(gA, gedges, ebase, dinv, Wc,
                                      bc, gB, hbuf, n, 0);
    k_layerB<<<nbB, 256, 0, stream>>>(gB, gedges, ebase, dinv, Wc + (size_t)H * H,
                                      bc + H, gA, hbuf, n, 0);
    k_layerB<<<nbB, 256, 0, stream>>>(gA, gedges, ebase, dinv, Wc + (size_t)2 * H * H,
                                      bc + 2 * H, gB, hbuf, n, 1);

    k_heads<<<(n + 63) / 64, 64, 0, stream>>>(hbuf, Wd1, bd1, Wd2, bd2,
                                              Wi1, bi1, Wi2, bi2, (float*)d_out, n);
}

// Round 14
// 401.568 us; speedup vs baseline: 5.6085x; 5.6085x over previous
//
#include <hip/hip_runtime.h>

#define H 64
#define FN 5
#define EPB 4096        // edges per scatter block
#define BSHIFT 8        // bucket = dst >> 8 (256 nodes per bucket)
#define CAP2 4864       // per-bucket edge staging (mean 4096, +12 sigma)

typedef _Float16 half4 __attribute__((ext_vector_type(4)));
typedef _Float16 half8 __attribute__((ext_vector_type(8)));
typedef float    float8v __attribute__((ext_vector_type(8)));

// ================= CSR build (r12: fastest correct variant) =================
__global__ void k_bscatter2(const int* __restrict__ src, const int* __restrict__ dst,
                            int* __restrict__ lofs_g, int* __restrict__ bcounts,
                            int* __restrict__ binned, int nE, int nbB) {
    __shared__ int lh[512], lpos[512], lcur[512], tmp[256];
    __shared__ int stage[EPB];             // 16 KB
    int t = threadIdx.x;
    int e0 = blockIdx.x * EPB;
    int es[16], ed[16];
    lh[t] = 0; lh[t + 256] = 0;
    __syncthreads();
#pragma unroll
    for (int i = 0; i < 16; ++i) {
        int e = e0 + i * 256 + t;
        bool v = e < nE;
        es[i] = v ? src[e] : 0;
        ed[i] = v ? dst[e] : -1;
        if (v) atomicAdd(&lh[ed[i] >> BSHIFT], 1);
    }
    __syncthreads();
    int a0 = lh[2 * t], a1 = lh[2 * t + 1];
    tmp[t] = a0 + a1;
    __syncthreads();
    for (int s = 1; s < 256; s <<= 1) {
        int a = (t >= s) ? tmp[t - s] : 0;
        __syncthreads();
        tmp[t] += a;
        __syncthreads();
    }
    int ex = tmp[t] - (a0 + a1);
    lpos[2 * t] = ex;
    lpos[2 * t + 1] = ex + a0;
    __syncthreads();
    lcur[t] = lpos[t]; lcur[t + 256] = lpos[t + 256];
    size_t row = (size_t)blockIdx.x * (nbB + 1);
    for (int b = t; b <= nbB; b += 256) lofs_g[row + b] = lpos[b];
    for (int b = t; b < nbB; b += 256) if (lh[b]) atomicAdd(&bcounts[b], lh[b]);
    __syncthreads();
#pragma unroll
    for (int i = 0; i < 16; ++i) {
        if (ed[i] >= 0) {
            int b = ed[i] >> BSHIFT;
            int p = atomicAdd(&lcur[b], 1);
            stage[p] = es[i] | ((ed[i] & 255) << 17);
        }
    }
    __syncthreads();
    int total = lpos[nbB];
    for (int j = t; j < total; j += 256) binned[e0 + j] = stage[j];   // coalesced
}

__global__ void k_bcsr2(const int* __restrict__ binned, const int* __restrict__ lofs_g,
                        const int* __restrict__ bcounts, int* __restrict__ row_ptr,
                        int* __restrict__ csr_src, float* __restrict__ dinv,
                        int n, int nE, int nbE, int nbB) {
    __shared__ int runlen[512], runstart[512], roff[512], tmp[256];
    __shared__ int deg[256], st[256], cur[256];
    __shared__ int sh_base, sh_total;
    __shared__ int lbuf[CAP2];      // 19 KB
    __shared__ int stage2[CAP2];    // 19 KB
    int t = threadIdx.x;
    int B = blockIdx.x;
    int node0 = B << BSHIFT;
    int nn = min(256, n - node0);

    int myb = 0;
    for (int b = t; b < B; b += 256) myb += bcounts[b];
    tmp[t] = myb;
    __syncthreads();
    for (int s = 128; s > 0; s >>= 1) {
        if (t < s) tmp[t] += tmp[t + s];
        __syncthreads();
    }
    if (t == 0) sh_base = tmp[0];

    runlen[t] = 0; runlen[t + 256] = 0;
    __syncthreads();
    for (int sb = t; sb < nbE; sb += 256) {
        size_t row = (size_t)sb * (nbB + 1);
        int o0 = lofs_g[row + B], o1 = lofs_g[row + B + 1];
        runlen[sb] = o1 - o0;
        runstart[sb] = sb * EPB + o0;
    }
    __syncthreads();
    int a0 = runlen[2 * t], a1 = runlen[2 * t + 1];
    tmp[t] = a0 + a1;
    __syncthreads();
    for (int s = 1; s < 256; s <<= 1) {
        int a = (t >= s) ? tmp[t - s] : 0;
        __syncthreads();
        tmp[t] += a;
        __syncthreads();
    }
    int ex = tmp[t] - (a0 + a1);
    roff[2 * t] = ex;
    roff[2 * t + 1] = ex + a0;
    if (t == 255) sh_total = tmp[255];
    __syncthreads();
    int total = min(sh_total, CAP2);

    for (int j = t; j < total; j += 256) {
        int lo = 0, hi = nbE - 1;
        while (lo < hi) {
            int mid = (lo + hi + 1) >> 1;
            if (roff[mid] <= j) lo = mid; else hi = mid - 1;
        }
        lbuf[j] = binned[runstart[lo] + (j - roff[lo])];
    }
    deg[t] = 0;
    __syncthreads();
    for (int i = t; i < total; i += 256) atomicAdd(&deg[(lbuf[i] >> 17) & 255], 1);
    __syncthreads();
    tmp[t] = deg[t];
    __syncthreads();
    for (int s = 1; s < 256; s <<= 1) {
        int a = (t >= s) ? tmp[t - s] : 0;
        __syncthreads();
        tmp[t] += a;
        __syncthreads();
    }
    st[t] = tmp[t] - deg[t];
    cur[t] = st[t];
    __syncthreads();
    int base = sh_base;
    if (t < nn) {
        row_ptr[node0 + t] = base + st[t];
        dinv[node0 + t] = 1.0f / sqrtf((float)deg[t] + 1.0f);
    }
    if (B == 0 && t == 0) row_ptr[n] = nE;
    for (int i = t; i < total; i += 256) {
        int p0 = lbuf[i];
        int p = atomicAdd(&cur[(p0 >> 17) & 255], 1);
        int sv = p0 & 0x1FFFF;
        if (p < CAP2) stage2[p] = sv;
        else csr_src[base + p] = sv;
    }
    __syncthreads();
    for (int i = t; i < total; i += 256) csr_src[base + i] = stage2[i];
}

// ================= encoder: g0 = fp16( dinv * relu(x@Wn+bn) ) =================
__global__ void k_enc(const float* __restrict__ x, const float* __restrict__ Wn,
                      const float* __restrict__ bn, const float* __restrict__ dinv,
                      _Float16* __restrict__ g0, int n) {
    int tid = blockIdx.x * 256 + threadIdx.x;
    int node = tid >> 6, ch = tid & 63;
    if (node >= n) return;
    float acc = bn[ch];
#pragma unroll
    for (int k = 0; k < FN; ++k)
        acc += x[(size_t)node * FN + k] * Wn[k * H + ch];
    g0[(size_t)node * H + ch] = (_Float16)(fmaxf(acc, 0.f) * dinv[node]);
}

// ================= fused layer (r9 shape — best measured: 66 us, FETCH 80 MB) ======
// 64 nodes/block, 256 threads (4 waves). Wave w handles node pairs
// (rA = it*8 + w, rB = rA + 4) for it = 0..7 — dual-stream gather (2x8
// scattered 128 B rows in flight), 8-slot x 8-chunk lane layout. The 64-node
// dst-grouping + moderate occupancy keeps the L2 working set small (r9's
// FETCH 80 MB vs ~150 MB for 16-node blocks / quad-stream variants).
__global__ void k_layer(const _Float16* __restrict__ gin, const int* __restrict__ csr_src,
                        const int* __restrict__ row_ptr, const float* __restrict__ dinv,
                        const float* __restrict__ W, const float* __restrict__ bias,
                        _Float16* __restrict__ gout, float* __restrict__ hout,
                        int n, int last) {
    __shared__ float As[64 * 68];
    __shared__ int rp_s[65];
    __shared__ float dv_s[64];
    int t = threadIdx.x;
    int wave = t >> 6, lane = t & 63;
    int base = blockIdx.x * 64;
    if (t < 65) rp_s[t] = row_ptr[min(base + t, n)];
    if (t >= 128 && t < 192) {
        int nd = base + (t - 128);
        dv_s[t - 128] = (nd < n) ? dinv[nd] : 0.f;
    }
    __syncthreads();

    int c8 = (lane >> 3) * 8;
    int slot = lane & 7;
    for (int it = 0; it < 8; ++it) {
        int rA = it * 8 + wave, rB = rA + 4;
        int nodeA = base + rA, nodeB = base + rB;
        float8v accA = 0.f, accB = 0.f;
        int iA = rp_s[rA], eA = rp_s[rA + 1];
        int iB = rp_s[rB], eB = rp_s[rB + 1];
        while (iA + 8 <= eA && iB + 8 <= eB) {
            int xA = csr_src[iA + slot];
            int xB = csr_src[iB + slot];
            half8 vA = *(const half8*)(gin + (size_t)xA * H + c8);
            half8 vB = *(const half8*)(gin + (size_t)xB * H + c8);
#pragma unroll
            for (int k = 0; k < 8; ++k) { accA[k] += (float)vA[k]; accB[k] += (float)vB[k]; }
            iA += 8; iB += 8;
        }
        while (iA + 8 <= eA) {
            int xA = csr_src[iA + slot];
            half8 vA = *(const half8*)(gin + (size_t)xA * H + c8);
#pragma unroll
            for (int k = 0; k < 8; ++k) accA[k] += (float)vA[k];
            iA += 8;
        }
        while (iB + 8 <= eB) {
            int xB = csr_src[iB + slot];
            half8 vB = *(const half8*)(gin + (size_t)xB * H + c8);
#pragma unroll
            for (int k = 0; k < 8; ++k) accB[k] += (float)vB[k];
            iB += 8;
        }
        if (iA + slot < eA) {
            int xA = csr_src[iA + slot];
            half8 vA = *(const half8*)(gin + (size_t)xA * H + c8);
#pragma unroll
            for (int k = 0; k < 8; ++k) accA[k] += (float)vA[k];
        }
        if (iB + slot < eB) {
            int xB = csr_src[iB + slot];
            half8 vB = *(const half8*)(gin + (size_t)xB * H + c8);
#pragma unroll
            for (int k = 0; k < 8; ++k) accB[k] += (float)vB[k];
        }
#pragma unroll
        for (int m = 1; m <= 4; m <<= 1) {
#pragma unroll
            for (int k = 0; k < 8; ++k) {
                accA[k] += __shfl_xor(accA[k], m, 64);
                accB[k] += __shfl_xor(accB[k], m, 64);
            }
        }
        if (slot == 0) {
            float oA[8], oB[8];
            if (nodeA < n) {
                half8 sA = *(const half8*)(gin + (size_t)nodeA * H + c8);
                float dA = dv_s[rA];
#pragma unroll
                for (int k = 0; k < 8; ++k) oA[k] = (accA[k] + (float)sA[k]) * dA;
            } else {
#pragma unroll
                for (int k = 0; k < 8; ++k) oA[k] = 0.f;
            }
            if (nodeB < n) {
                half8 sB = *(const half8*)(gin + (size_t)nodeB * H + c8);
                float dB = dv_s[rB];
#pragma unroll
                for (int k = 0; k < 8; ++k) oB[k] = (accB[k] + (float)sB[k]) * dB;
            } else {
#pragma unroll
                for (int k = 0; k < 8; ++k) oB[k] = 0.f;
            }
            *(float4*)&As[rA * 68 + c8]     = make_float4(oA[0], oA[1], oA[2], oA[3]);
            *(float4*)&As[rA * 68 + c8 + 4] = make_float4(oA[4], oA[5], oA[6], oA[7]);
            *(float4*)&As[rB * 68 + c8]     = make_float4(oB[0], oB[1], oB[2], oB[3]);
            *(float4*)&As[rB * 68 + c8 + 4] = make_float4(oB[4], oB[5], oB[6], oB[7]);
        }
    }
    __syncthreads();

    // phase 2: 4x4 register-tile GEMM, W from global (L1-hot)
    int tx = t & 15, ty = t >> 4;
    int c0 = tx * 4;
    const float* a0 = As + (ty * 4 + 0) * 68;
    const float* a1 = As + (ty * 4 + 1) * 68;
    const float* a2 = As + (ty * 4 + 2) * 68;
    const float* a3 = As + (ty * 4 + 3) * 68;
    float4 acc0 = make_float4(0.f, 0.f, 0.f, 0.f);
    float4 acc1 = acc0, acc2 = acc0, acc3 = acc0;
#pragma unroll 16
    for (int k = 0; k < H; ++k) {
        float4 w = *(const float4*)(W + k * H + c0);
        float v0 = a0[k], v1 = a1[k], v2 = a2[k], v3 = a3[k];
        acc0.x += v0 * w.x; acc0.y += v0 * w.y; acc0.z += v0 * w.z; acc0.w += v0 * w.w;
        acc1.x += v1 * w.x; acc1.y += v1 * w.y; acc1.z += v1 * w.z; acc1.w += v1 * w.w;
        acc2.x += v2 * w.x; acc2.y += v2 * w.y; acc2.z += v2 * w.z; acc2.w += v2 * w.w;
        acc3.x += v3 * w.x; acc3.y += v3 * w.y; acc3.z += v3 * w.z; acc3.w += v3 * w.w;
    }
    float4 b = *(const float4*)(bias + c0);
    float4 accs[4] = {acc0, acc1, acc2, acc3};
#pragma unroll
    for (int rr = 0; rr < 4; ++rr) {
        int r = ty * 4 + rr;
        int row = base + r;
        if (row < n) {
            float4 o;
            o.x = fmaxf(accs[rr].x + b.x, 0.f);
            o.y = fmaxf(accs[rr].y + b.y, 0.f);
            o.z = fmaxf(accs[rr].z + b.z, 0.f);
            o.w = fmaxf(accs[rr].w + b.w, 0.f);
            if (last) {
                *(float4*)(hout + (size_t)row * H + c0) = o;
            } else {
                float d = dv_s[r];
                half4 hh;
                hh.x = (_Float16)(o.x * d);
                hh.y = (_Float16)(o.y * d);
                hh.z = (_Float16)(o.z * d);
                hh.w = (_Float16)(o.w * d);
                *(half4*)(gout + (size_t)row * H + c0) = hh;
            }
        }
    }
}

// ================= heads (lane = node) =================
__global__ void k_heads(const float* __restrict__ h,
                        const float* __restrict__ Wd1, const float* __restrict__ bd1,
                        const float* __restrict__ Wd2, const float* __restrict__ bd2,
                        const float* __restrict__ Wi1, const float* __restrict__ bi1,
                        const float* __restrict__ Wi2, const float* __restrict__ bi2,
                        float* __restrict__ out, int n) {
    __shared__ float hs[64 * 65];
    int lane = threadIdx.x;          // blockDim = 64
    int base = blockIdx.x * 64;
    for (int r = 0; r < 64; ++r) {
        int row = base + r;
        hs[r * 65 + lane] = (row < n) ? h[(size_t)row * H + lane] : 0.f;
    }
    __syncthreads();

    float accd[32], acci[32];
#pragma unroll
    for (int j = 0; j < 32; ++j) { accd[j] = bd1[j]; acci[j] = bi1[j]; }
    for (int k = 0; k < H; ++k) {
        float hk = hs[lane * 65 + k];
#pragma unroll
        for (int j = 0; j < 32; ++j) {
            accd[j] += hk * Wd1[k * 32 + j];
            acci[j] += hk * Wi1[k * 32 + j];
        }
    }
    float demand = bd2[0], inventory = bi2[0];
#pragma unroll
    for (int j = 0; j < 32; ++j) {
        demand    += fmaxf(accd[j], 0.f) * Wd2[j];
        inventory += fmaxf(acci[j], 0.f) * Wi2[j];
    }
    int node = base + lane;
    if (node < n) {
        out[node] = demand;
        out[n + node] = inventory;
    }
}

extern "C" void kernel_launch(void* const* d_in, const int* in_sizes, int n_in,
                              void* d_out, int out_size, void* d_ws, size_t ws_size,
                              hipStream_t stream) {
    const float* x   = (const float*)d_in[0];
    const int*   ei  = (const int*)  d_in[1];
    // d_in[2] = edge_attr, d_in[5] = We, d_in[6] = be : dead code in reference.
    const float* Wn  = (const float*)d_in[3];
    const float* bn  = (const float*)d_in[4];
    const float* Wc  = (const float*)d_in[7];   // [3,64,64]
    const float* bc  = (const float*)d_in[8];   // [3,64]
    const float* Wd1 = (const float*)d_in[9];
    const float* bd1 = (const float*)d_in[10];
    const float* Wd2 = (const float*)d_in[11];
    const float* bd2 = (const float*)d_in[12];
    const float* Wi1 = (const float*)d_in[13];
    const float* bi1 = (const float*)d_in[14];
    const float* Wi2 = (const float*)d_in[15];
    const float* bi2 = (const float*)d_in[16];

    const int n  = in_sizes[0] / FN;   // 100000
    const int nE = in_sizes[1] / 2;    // 1600000
    const int* src = ei;
    const int* dst = ei + nE;

    const int nbE = (nE + EPB - 1) / EPB;       // 391 scatter blocks
    const int nbB = (n + 255) >> BSHIFT;        // 391 buckets
    const int nbL = (n + 63) / 64;              // 1563

    char* w = (char*)d_ws;
    int* binned    = (int*)w;   w += (size_t)nbE * EPB * 4;
    int* csr_src   = (int*)w;   w += (size_t)nE * 4;
    int* row_ptr   = (int*)w;   w += (size_t)(n + 4) * 4;
    float* dinv    = (float*)w; w += (size_t)n * 4;
    int* lofs      = (int*)w;   w += (size_t)nbE * (nbB + 1) * 4;
    int* bcounts   = (int*)w;   w += 512 * 4;
    float* hbuf    = (float*)w; w += (size_t)n * H * 4;
    _Float16* gA   = (_Float16*)w; w += (size_t)n * H * 2;
    _Float16* gB   = (_Float16*)w; w += (size_t)n * H * 2;

    hipMemsetAsync(bcounts, 0, 512 * 4, stream);

    k_bscatter2<<<nbE, 256, 0, stream>>>(src, dst, lofs, bcounts, binned, nE, nbB);
    k_bcsr2    <<<nbB, 256, 0, stream>>>(binned, lofs, bcounts, row_ptr, csr_src,
                                         dinv, n, nE, nbE, nbB);

    k_enc<<<((size_t)n * 64 + 255) / 256, 256, 0, stream>>>(x, Wn, bn, dinv, gA, n);

    k_layer<<<nbL, 256, 0, stream>>>(gA, csr_src, row_ptr, dinv, Wc,
                                     bc, gB, hbuf, n, 0);
    k_layer<<<nbL, 256, 0, stream>>>(gB, csr_src, row_ptr, dinv, Wc + (size_t)H * H,
                                     bc + H, gA, hbuf, n, 0);
    k_layer<<<nbL, 256, 0, stream>>>(gA, csr_src, row_ptr, dinv, Wc + (size_t)2 * H * H,
                                     bc + 2 * H, gB, hbuf, n, 1);

    k_heads<<<(n + 63) / 64, 64, 0, stream>>>(hbuf, Wd1, bd1, Wd2, bd2,
                                              Wi1, bi1, Wi2, bi2, (float*)d_out, n);
}